// Round 7
// baseline (237.997 us; speedup 1.0000x reference)
//
#include <hip/hip_runtime.h>
#include <stdint.h>

#define T_SEQ 2048
#define D_MODEL 1024
#define NH 16
#define DH 64
#define NROWS 4096  // B*T

typedef __bf16 bf16x8 __attribute__((ext_vector_type(8)));
typedef float floatx4 __attribute__((ext_vector_type(4)));
typedef short short4v __attribute__((ext_vector_type(4)));
typedef short short8v __attribute__((ext_vector_type(8)));

#define AS1 __attribute__((address_space(1)))
#define AS3 __attribute__((address_space(3)))

static __device__ __forceinline__ void gl2lds16(const unsigned short* g, unsigned short* s) {
    __builtin_amdgcn_global_load_lds((const AS1 unsigned int*)g, (AS3 unsigned int*)s, 16, 0, 0);
}

static __device__ __forceinline__ unsigned short f32_bf16(float f) {
    union { float f; unsigned int u; } c; c.f = f;
    unsigned int u = c.u;
    u = u + 0x7FFFu + ((u >> 16) & 1u);   // RNE
    return (unsigned short)(u >> 16);
}

static __device__ __forceinline__ unsigned int pack2_bf16(float a, float b) {
    return (unsigned int)f32_bf16(a) | ((unsigned int)f32_bf16(b) << 16);
}

static __device__ __forceinline__ floatx4 mfma16(bf16x8 a, bf16x8 b, floatx4 c) {
    return __builtin_amdgcn_mfma_f32_16x16x32_bf16(a, b, c, 0, 0, 0);
}

static __device__ __forceinline__ floatx4 mfma16k16(short4v a, short4v b, floatx4 c) {
#if defined(__HIP_DEVICE_COMPILE__)
    return __builtin_amdgcn_mfma_f32_16x16x16bf16_1k(a, b, c, 0, 0, 0);
#else
    (void)a; (void)b;
    return c;  // host stub — never executed
#endif
}

#define QSCALE 0.1803368801111204f   // (1/8) * log2(e); softmax in exp2 domain
#define EXP2_SHIFT 10.0f
// s_waitcnt imm: vmcnt[3:0]|[15:14]=0, expcnt[6:4]=7 (nowait), lgkmcnt[11:8]=0xF (nowait)
#define WAITCNT_VM0 0x0F70

// ---------------- fused conversion kernel ----------------
// blocks 0..4095: x fp32->bf16; 4096..7167: Wq/Wk/Wv row-permute; 7168..8191: Wo col-permute
__global__ __launch_bounds__(256) void k_conv_all(const float* __restrict__ x,
                                                  const float* __restrict__ Wq,
                                                  const float* __restrict__ Wk,
                                                  const float* __restrict__ Wv,
                                                  const float* __restrict__ Wo,
                                                  unsigned short* __restrict__ x_bf,
                                                  unsigned short* __restrict__ wqkv_bf,
                                                  unsigned short* __restrict__ wo_bf) {
    int b = blockIdx.x, t = threadIdx.x;
    if (b < 4096) {
        int i = b * 1024 + t * 4;
        float4 v = *(const float4*)(x + i);
        uint2 o;
        o.x = pack2_bf16(v.x, v.y);
        o.y = pack2_bf16(v.z, v.w);
        *(uint2*)(x_bf + i) = o;
    } else if (b < 7168) {
        int idx = b - 4096;
        int tensor = idx >> 10, np = idx & 1023;
        const float* src = tensor == 0 ? Wq : tensor == 1 ? Wk : Wv;
        int f = (np & 63) * 16 + (np >> 6);
        int c = t * 4;
        float4 v = *(const float4*)(src + (long)f * D_MODEL + c);
        uint2 o;
        o.x = pack2_bf16(v.x, v.y);
        o.y = pack2_bf16(v.z, v.w);
        *(uint2*)(wqkv_bf + ((long)tensor * D_MODEL + np) * D_MODEL + c) = o;
    } else {
        int n = b - 7168;
        int fp = t * 4;
        const float* row = Wo + (long)n * D_MODEL;
        unsigned short o[4];
        #pragma unroll
        for (int k = 0; k < 4; k++) {
            int f = fp + k;
            o[k] = f32_bf16(row[(f & 63) * 16 + (f >> 6)]);
        }
        *(uint2*)(wo_bf + (long)n * D_MODEL + fp) = *(const uint2*)o;
    }
}

// ---------------- GEMM: C = A(bf16) @ W(bf16)^T, K = 1024 ----------------
// BM=128, BK=64, 256 threads = 4 waves 2x2; XOR-swizzled LDS (conflict-free frag reads
// while keeping global_load_lds lane-order); XCD-aware 1D block swizzle.
// MODE 0: fused QKV (W stacked 3072x1024); grid 768. MODE 1: O-proj; grid 512.
template <int BN, int MODE>
__global__ __launch_bounds__(256) void k_gemm(const unsigned short* __restrict__ A,
                                              const unsigned short* __restrict__ W,
                                              const float* __restrict__ b0,
                                              const float* __restrict__ b1,
                                              const float* __restrict__ b2,
                                              const float* __restrict__ resid,
                                              unsigned short* __restrict__ out_bf,
                                              unsigned short* __restrict__ vtg,
                                              float* __restrict__ out_f32) {
    constexpr int NT = BN / 32;
    constexpr int NCB = BN / 32;
    __shared__ unsigned short lds_a[128 * 64];
    __shared__ unsigned short lds_b[BN * 64];
    const int tid = threadIdx.x;
    const int w = tid >> 6, l = tid & 63;
    const int lrow = l & 15, lq = l >> 4;
    const int wm = (w >> 1) * 64, wn = (w & 1) * (BN / 2);
    // XCD swizzle: same x-tile stays on one XCD (assumes xcd = linearID % 8)
    const int L = blockIdx.x;
    const int bx = (L & 7) * 4 + ((L >> 3) & 3);
    const int by = L >> 5;
    const long am0 = (long)bx * 128;
    const long wn0 = (long)by * BN;

    floatx4 acc[4][NT] = {};
    const int grow = l >> 3;
    const int gcol = ((l & 7) ^ grow) * 8;    // column-group XOR swizzle on the global side
    const int sw8 = (lrow & 7);

    for (int k0 = 0; k0 < D_MODEL; k0 += 64) {
        #pragma unroll
        for (int c = 0; c < 4; c++) {
            int chunk = w * 4 + c;
            gl2lds16(A + (am0 + chunk * 8 + grow) * D_MODEL + k0 + gcol,
                     lds_a + chunk * 512);
        }
        #pragma unroll
        for (int c = 0; c < NCB; c++) {
            int chunk = w * NCB + c;
            gl2lds16(W + (wn0 + chunk * 8 + grow) * D_MODEL + k0 + gcol,
                     lds_b + chunk * 512);
        }
        __syncthreads();

        bf16x8 af[4][2], bf[NT][2];
        #pragma unroll
        for (int mt = 0; mt < 4; mt++)
            #pragma unroll
            for (int ks = 0; ks < 2; ks++)
                af[mt][ks] = *(const bf16x8*)(lds_a + (wm + mt * 16 + lrow) * 64 +
                                              (((ks * 4 + lq) ^ sw8) * 8));
        #pragma unroll
        for (int nt = 0; nt < NT; nt++)
            #pragma unroll
            for (int ks = 0; ks < 2; ks++)
                bf[nt][ks] = *(const bf16x8*)(lds_b + (wn + nt * 16 + lrow) * 64 +
                                              (((ks * 4 + lq) ^ sw8) * 8));
        #pragma unroll
        for (int mt = 0; mt < 4; mt++)
            #pragma unroll
            for (int nt = 0; nt < NT; nt++)
                #pragma unroll
                for (int ks = 0; ks < 2; ks++)
                    acc[mt][nt] = mfma16(af[mt][ks], bf[nt][ks], acc[mt][nt]);
        __syncthreads();
    }

    if (MODE == 0) {
        int tensor = by >> 3;                    // 0=Q 1=K 2=V
        int nbase = (by & 7) * 128;
        const float* bias = tensor == 0 ? b0 : tensor == 1 ? b1 : b2;
        float scale = tensor == 0 ? QSCALE : 1.0f;
        if (tensor < 2) {
            unsigned short* outt = out_bf + (size_t)tensor * (32u * T_SEQ * DH);
            #pragma unroll
            for (int mt = 0; mt < 4; mt++) {
                #pragma unroll
                for (int nt = 0; nt < NT; nt++) {
                    int n = nbase + wn + nt * 16 + lrow;     // n' = h*64+d
                    int h = n >> 6, d = n & 63;
                    float bb = bias[d * 16 + h];
                    #pragma unroll
                    for (int r = 0; r < 4; r++) {
                        int row = (int)am0 + wm + mt * 16 + lq * 4 + r;
                        float v = (acc[mt][nt][r] + bb) * scale;
                        int b = row >> 11, i = row & 2047;
                        long idx = ((long)(b * 16 + h) * T_SEQ + i) * DH + d;
                        outt[idx] = f32_bf16(v);
                    }
                }
            }
        } else {
            // V -> vtg[((bh*64+d)*32 + blk)*64 + j'], j' = lq*16 + mt*4 + r
            int row0 = (int)am0 + wm;                    // multiple of 64
            int b = row0 >> 11;
            int blk = (row0 & 2047) >> 6;
            #pragma unroll
            for (int nt = 0; nt < NT; nt++) {
                int n = nbase + wn + nt * 16 + lrow;
                int h = n >> 6, d = n & 63;
                float bb = bias[d * 16 + h];
                long base = (((long)(b * 16 + h) * 64 + d) * 32 + blk) * 64;
                #pragma unroll
                for (int mt = 0; mt < 4; mt++) {
                    uint2 o;
                    o.x = pack2_bf16(acc[mt][nt][0] + bb, acc[mt][nt][1] + bb);
                    o.y = pack2_bf16(acc[mt][nt][2] + bb, acc[mt][nt][3] + bb);
                    *(uint2*)(vtg + base + lq * 16 + mt * 4) = o;
                }
            }
        }
    } else {
        #pragma unroll
        for (int mt = 0; mt < 4; mt++) {
            #pragma unroll
            for (int nt = 0; nt < NT; nt++) {
                int n = (int)wn0 + wn + nt * 16 + lrow;
                float bb = b0[n];
                #pragma unroll
                for (int r = 0; r < 4; r++) {
                    int row = (int)am0 + wm + mt * 16 + lq * 4 + r;
                    long idx = (long)row * D_MODEL + n;
                    out_f32[idx] = acc[mt][nt][r] + bb + resid[idx];
                }
            }
        }
    }
}

// ---------------- attention: S^T trick, K direct from global, V async in LDS ------
// K-frag lane layout == contiguous 16B rows of k_ws -> load K straight from global
// (L1/L2-served; all 4 waves share the same K tile). Only V is staged in LDS:
// double-buffered via global_load_lds; the S-phase K-waits retire the V-DMA
// implicitly (vmcnt retires in-order, V-DMA issued before K loads), so one plain
// __syncthreads() per iteration suffices and its vmcnt drain is empty.
__global__ __launch_bounds__(256) void k_attn(const unsigned short* __restrict__ q_ws,
                                              const unsigned short* __restrict__ k_ws,
                                              const unsigned short* __restrict__ vtg,
                                              unsigned short* __restrict__ att) {
    __shared__ unsigned short vbuf[2 * 64 * 64];   // 16 KB
    const int tid = threadIdx.x;
    const int w = tid >> 6, l = tid & 63;
    const int lrow = l & 15, lq = l >> 4;
    const int sw = lrow & 7;
    const int L = blockIdx.x;
    const int bh = (L & 7) * 4 + ((L >> 3) & 3);   // 4 bh per XCD -> K/V L2-resident
    const int i0 = (L >> 5) * 128;
    const unsigned short* kh = k_ws + (long)bh * T_SEQ * DH;
    const unsigned short* vh = vtg + (long)bh * 64 * T_SEQ;  // [d][blk][j']

    const int rl = l >> 3;                     // staging: row within 8-row chunk
    const int gl = ((l & 7) ^ rl) * 8;         // staging: swizzled granule (shorts)

    bf16x8 qf[2][2];
    #pragma unroll
    for (int qt = 0; qt < 2; qt++) {
        const unsigned short* qp =
            q_ws + ((long)bh * T_SEQ + i0 + w * 32 + qt * 16 + lrow) * DH + lq * 8;
        qf[qt][0] = *(const bf16x8*)qp;
        qf[qt][1] = *(const bf16x8*)(qp + 32);
    }
    floatx4 o_acc[2][4] = {};
    floatx4 l_acc[2] = {};
    const short4v ones = {0x3F80, 0x3F80, 0x3F80, 0x3F80};

    // stage V tile jt into buffer sel (2 global_load_lds per thread)
    auto stage = [&](int jt, int sel) {
        unsigned short* vd = vbuf + sel * 4096 + (w * 2) * 512;
        #pragma unroll
        for (int c = 0; c < 2; c++) {
            int row = w * 16 + c * 8 + rl;     // 0..63 (d index)
            gl2lds16(vh + ((long)row * 32 + jt) * 64 + gl, vd + c * 512);
        }
    };

    stage(0, 0);
    __builtin_amdgcn_s_waitcnt(WAITCNT_VM0);   // prologue only: make tile 0 visible
    __syncthreads();

    for (int jt = 0; jt < T_SEQ / 64; jt++) {
        const int cur = jt & 1;
        if (jt < T_SEQ / 64 - 1) stage(jt + 1, 1 - cur);   // V prefetch (oldest in queue)

        const unsigned short* vb_ = vbuf + cur * 4096;
        const unsigned short* kp0 = kh + ((long)(jt * 64 + lrow)) * 64 + lq * 8;

        // S^T - 10 for both q-tiles; K-frags loaded straight from global (L1-shared)
        floatx4 s0[4], s1[4];
        #pragma unroll
        for (int nt = 0; nt < 4; nt++) {
            bf16x8 ka = *(const bf16x8*)(kp0 + nt * 1024);
            bf16x8 kb = *(const bf16x8*)(kp0 + nt * 1024 + 32);
            floatx4 c0 = {-EXP2_SHIFT, -EXP2_SHIFT, -EXP2_SHIFT, -EXP2_SHIFT};
            floatx4 c1 = c0;
            c0 = mfma16(ka, qf[0][0], c0);
            c0 = mfma16(kb, qf[0][1], c0);
            c1 = mfma16(ka, qf[1][0], c1);
            c1 = mfma16(kb, qf[1][1], c1);
            s0[nt] = c0;
            s1[nt] = c1;
        }
        // p = exp2(s); pack bf16 B-frags; denominators via ones-MFMA
        short4v pf0[4], pf1[4];
        #pragma unroll
        for (int nt = 0; nt < 4; nt++) {
            {
                float p0 = __builtin_amdgcn_exp2f(s0[nt][0]);
                float p1 = __builtin_amdgcn_exp2f(s0[nt][1]);
                float p2 = __builtin_amdgcn_exp2f(s0[nt][2]);
                float p3 = __builtin_amdgcn_exp2f(s0[nt][3]);
                uint2 pk;
                pk.x = __builtin_amdgcn_perm(__float_as_uint(p1), __float_as_uint(p0), 0x07060302);
                pk.y = __builtin_amdgcn_perm(__float_as_uint(p3), __float_as_uint(p2), 0x07060302);
                union { uint2 u; short4v s4; } cv; cv.u = pk;
                pf0[nt] = cv.s4;
                l_acc[0] = mfma16k16(ones, pf0[nt], l_acc[0]);
            }
            {
                float p0 = __builtin_amdgcn_exp2f(s1[nt][0]);
                float p1 = __builtin_amdgcn_exp2f(s1[nt][1]);
                float p2 = __builtin_amdgcn_exp2f(s1[nt][2]);
                float p3 = __builtin_amdgcn_exp2f(s1[nt][3]);
                uint2 pk;
                pk.x = __builtin_amdgcn_perm(__float_as_uint(p1), __float_as_uint(p0), 0x07060302);
                pk.y = __builtin_amdgcn_perm(__float_as_uint(p3), __float_as_uint(p2), 0x07060302);
                union { uint2 u; short4v s4; } cv; cv.u = pk;
                pf1[nt] = cv.s4;
                l_acc[1] = mfma16k16(ones, pf1[nt], l_acc[1]);
            }
        }
        // O^T += V^T * P — V-frags read once from LDS (swizzled, conflict-free)
        #pragma unroll
        for (int dt = 0; dt < 4; dt++) {
            const unsigned short* vp = vb_ + (dt * 16 + lrow) * 64;
            short8v v01 = *(const short8v*)(vp + (((2 * lq) ^ sw) * 8));
            short8v v23 = *(const short8v*)(vp + (((2 * lq + 1) ^ sw) * 8));
            short4v va = __builtin_shufflevector(v01, v01, 0, 1, 2, 3);
            short4v vb = __builtin_shufflevector(v01, v01, 4, 5, 6, 7);
            short4v vc = __builtin_shufflevector(v23, v23, 0, 1, 2, 3);
            short4v vd = __builtin_shufflevector(v23, v23, 4, 5, 6, 7);
            o_acc[0][dt] = mfma16k16(va, pf0[0], o_acc[0][dt]);
            o_acc[0][dt] = mfma16k16(vb, pf0[1], o_acc[0][dt]);
            o_acc[0][dt] = mfma16k16(vc, pf0[2], o_acc[0][dt]);
            o_acc[0][dt] = mfma16k16(vd, pf0[3], o_acc[0][dt]);
            o_acc[1][dt] = mfma16k16(va, pf1[0], o_acc[1][dt]);
            o_acc[1][dt] = mfma16k16(vb, pf1[1], o_acc[1][dt]);
            o_acc[1][dt] = mfma16k16(vc, pf1[2], o_acc[1][dt]);
            o_acc[1][dt] = mfma16k16(vd, pf1[3], o_acc[1][dt]);
        }
        __syncthreads();   // vmcnt drain is empty (K-waits already retired the V-DMA)
    }
    int h = bh & 15, b = bh >> 4;
    #pragma unroll
    for (int qt = 0; qt < 2; qt++) {
        float rl2 = 1.0f / l_acc[qt][0];
        int i = i0 + w * 32 + qt * 16 + lrow;
        unsigned short* orow = att + ((long)(b * T_SEQ + i)) * D_MODEL + h * 64;
        #pragma unroll
        for (int dt = 0; dt < 4; dt++) {
            uint2 o;
            o.x = pack2_bf16(o_acc[qt][dt][0] * rl2, o_acc[qt][dt][1] * rl2);
            o.y = pack2_bf16(o_acc[qt][dt][2] * rl2, o_acc[qt][dt][3] * rl2);
            *(uint2*)(orow + dt * 16 + lq * 4) = o;
        }
    }
}

// ---------------- LayerNorm in-place on d_out ----------------
__global__ __launch_bounds__(256) void k_ln(float* __restrict__ io,
                                            const float* __restrict__ gamma,
                                            const float* __restrict__ beta) {
    int row = blockIdx.x, t = threadIdx.x;
    float* p = io + (long)row * D_MODEL + t * 4;
    float4 v = *(float4*)p;
    float s = v.x + v.y + v.z + v.w;
    float ss = v.x * v.x + v.y * v.y + v.z * v.z + v.w * v.w;
    #pragma unroll
    for (int m = 1; m < 64; m <<= 1) {
        s += __shfl_xor(s, m);
        ss += __shfl_xor(ss, m);
    }
    __shared__ float red[8];
    if ((t & 63) == 0) { red[t >> 6] = s; red[4 + (t >> 6)] = ss; }
    __syncthreads();
    s = red[0] + red[1] + red[2] + red[3];
    ss = red[4] + red[5] + red[6] + red[7];
    float mu = s * (1.0f / 1024.0f);
    float var = ss * (1.0f / 1024.0f) - mu * mu;
    float rstd = rsqrtf(var + 1e-5f);
    float4 g = *(const float4*)(gamma + t * 4);
    float4 be = *(const float4*)(beta + t * 4);
    float4 o;
    o.x = (v.x - mu) * rstd * g.x + be.x;
    o.y = (v.y - mu) * rstd * g.y + be.y;
    o.z = (v.z - mu) * rstd * g.z + be.z;
    o.w = (v.w - mu) * rstd * g.w + be.w;
    *(float4*)p = o;
}

extern "C" void kernel_launch(void* const* d_in, const int* in_sizes, int n_in,
                              void* d_out, int out_size, void* d_ws, size_t ws_size,
                              hipStream_t stream) {
    const float* x = (const float*)d_in[0];
    const float* Wq = (const float*)d_in[1];
    const float* bq = (const float*)d_in[2];
    const float* Wk = (const float*)d_in[3];
    const float* bk = (const float*)d_in[4];
    const float* Wv = (const float*)d_in[5];
    const float* bv = (const float*)d_in[6];
    const float* Wo = (const float*)d_in[7];
    const float* bo = (const float*)d_in[8];
    const float* gamma = (const float*)d_in[9];
    const float* beta = (const float*)d_in[10];
    float* out = (float*)d_out;

    char* ws = (char*)d_ws;
    unsigned short* x_bf = (unsigned short*)(ws);                       // 8 MB (reused as att)
    unsigned short* wqkv_bf = (unsigned short*)(ws + ((size_t)8 << 20));// 6 MB
    unsigned short* wo_bf = (unsigned short*)(ws + ((size_t)14 << 20)); // 2 MB
    unsigned short* qkv_ws = (unsigned short*)(ws + ((size_t)16 << 20));// 24 MB (q|k|vt)
    unsigned short* att = x_bf;  // alias: x_bf dead after QKV GEMM

    unsigned short* q_ws = qkv_ws;
    unsigned short* k_ws = qkv_ws + (size_t)32 * T_SEQ * DH;
    unsigned short* vtg = qkv_ws + (size_t)64 * T_SEQ * DH;

    k_conv_all<<<8192, 256, 0, stream>>>(x, Wq, Wk, Wv, Wo, x_bf, wqkv_bf, wo_bf);

    // fused QKV GEMM: N = 3072, 1D grid with XCD swizzle
    k_gemm<128, 0><<<768, 256, 0, stream>>>(
        x_bf, wqkv_bf, bq, bk, bv, nullptr, qkv_ws, vtg, nullptr);

    k_attn<<<512, 256, 0, stream>>>(q_ws, k_ws, vtg, att);

    // O-projection + bias + residual: N = 1024, 1D grid with XCD swizzle
    k_gemm<64, 1><<<512, 256, 0, stream>>>(
        att, wo_bf, bo, nullptr, nullptr, x, nullptr, nullptr, out);

    k_ln<<<NROWS, 256, 0, stream>>>(out, gamma, beta);
}

// Round 8
// 222.409 us; speedup vs baseline: 1.0701x; 1.0701x over previous
//
#include <hip/hip_runtime.h>
#include <stdint.h>

#define T_SEQ 2048
#define D_MODEL 1024
#define NH 16
#define DH 64
#define NROWS 4096  // B*T

typedef __bf16 bf16x8 __attribute__((ext_vector_type(8)));
typedef float floatx4 __attribute__((ext_vector_type(4)));
typedef short short4v __attribute__((ext_vector_type(4)));
typedef short short8v __attribute__((ext_vector_type(8)));

#define AS1 __attribute__((address_space(1)))
#define AS3 __attribute__((address_space(3)))

static __device__ __forceinline__ void gl2lds16(const unsigned short* g, unsigned short* s) {
    __builtin_amdgcn_global_load_lds((const AS1 unsigned int*)g, (AS3 unsigned int*)s, 16, 0, 0);
}

static __device__ __forceinline__ unsigned short f32_bf16(float f) {
    union { float f; unsigned int u; } c; c.f = f;
    unsigned int u = c.u;
    u = u + 0x7FFFu + ((u >> 16) & 1u);   // RNE
    return (unsigned short)(u >> 16);
}

static __device__ __forceinline__ unsigned int pack2_bf16(float a, float b) {
    return (unsigned int)f32_bf16(a) | ((unsigned int)f32_bf16(b) << 16);
}

static __device__ __forceinline__ floatx4 mfma16(bf16x8 a, bf16x8 b, floatx4 c) {
    return __builtin_amdgcn_mfma_f32_16x16x32_bf16(a, b, c, 0, 0, 0);
}

static __device__ __forceinline__ floatx4 mfma16k16(short4v a, short4v b, floatx4 c) {
#if defined(__HIP_DEVICE_COMPILE__)
    return __builtin_amdgcn_mfma_f32_16x16x16bf16_1k(a, b, c, 0, 0, 0);
#else
    (void)a; (void)b;
    return c;  // host stub — never executed
#endif
}

#define QSCALE 0.1803368801111204f   // (1/8) * log2(e); softmax in exp2 domain
#define EXP2_SHIFT 10.0f
// s_waitcnt imm: vmcnt[3:0]|[15:14], expcnt[6:4]=7 (nowait), lgkmcnt[11:8]=0xF (nowait)
#define WAITCNT_VM4 0x0F74
#define WAITCNT_VM0 0x0F70

// ---------------- fused conversion kernel ----------------
__global__ __launch_bounds__(256) void k_conv_all(const float* __restrict__ x,
                                                  const float* __restrict__ Wq,
                                                  const float* __restrict__ Wk,
                                                  const float* __restrict__ Wv,
                                                  const float* __restrict__ Wo,
                                                  unsigned short* __restrict__ x_bf,
                                                  unsigned short* __restrict__ wqkv_bf,
                                                  unsigned short* __restrict__ wo_bf) {
    int b = blockIdx.x, t = threadIdx.x;
    if (b < 4096) {
        int i = b * 1024 + t * 4;
        float4 v = *(const float4*)(x + i);
        uint2 o;
        o.x = pack2_bf16(v.x, v.y);
        o.y = pack2_bf16(v.z, v.w);
        *(uint2*)(x_bf + i) = o;
    } else if (b < 7168) {
        int idx = b - 4096;
        int tensor = idx >> 10, np = idx & 1023;
        const float* src = tensor == 0 ? Wq : tensor == 1 ? Wk : Wv;
        int f = (np & 63) * 16 + (np >> 6);
        int c = t * 4;
        float4 v = *(const float4*)(src + (long)f * D_MODEL + c);
        uint2 o;
        o.x = pack2_bf16(v.x, v.y);
        o.y = pack2_bf16(v.z, v.w);
        *(uint2*)(wqkv_bf + ((long)tensor * D_MODEL + np) * D_MODEL + c) = o;
    } else {
        int n = b - 7168;
        int fp = t * 4;
        const float* row = Wo + (long)n * D_MODEL;
        unsigned short o[4];
        #pragma unroll
        for (int k = 0; k < 4; k++) {
            int f = fp + k;
            o[k] = f32_bf16(row[(f & 63) * 16 + (f >> 6)]);
        }
        *(uint2*)(wo_bf + (long)n * D_MODEL + fp) = *(const uint2*)o;
    }
}

// ---------------- GEMM: C = A(bf16) @ W(bf16)^T, K = 1024 ----------------
template <int BN, int MODE>
__global__ __launch_bounds__(256) void k_gemm(const unsigned short* __restrict__ A,
                                              const unsigned short* __restrict__ W,
                                              const float* __restrict__ b0,
                                              const float* __restrict__ b1,
                                              const float* __restrict__ b2,
                                              const float* __restrict__ resid,
                                              unsigned short* __restrict__ out_bf,
                                              unsigned short* __restrict__ vtg,
                                              float* __restrict__ out_f32) {
    constexpr int NT = BN / 32;
    constexpr int NCB = BN / 32;
    __shared__ unsigned short lds_a[128 * 64];
    __shared__ unsigned short lds_b[BN * 64];
    const int tid = threadIdx.x;
    const int w = tid >> 6, l = tid & 63;
    const int lrow = l & 15, lq = l >> 4;
    const int wm = (w >> 1) * 64, wn = (w & 1) * (BN / 2);
    const int L = blockIdx.x;
    const int bx = (L & 7) * 4 + ((L >> 3) & 3);
    const int by = L >> 5;
    const long am0 = (long)bx * 128;
    const long wn0 = (long)by * BN;

    floatx4 acc[4][NT] = {};
    const int grow = l >> 3;
    const int gcol = ((l & 7) ^ grow) * 8;
    const int sw8 = (lrow & 7);

    for (int k0 = 0; k0 < D_MODEL; k0 += 64) {
        #pragma unroll
        for (int c = 0; c < 4; c++) {
            int chunk = w * 4 + c;
            gl2lds16(A + (am0 + chunk * 8 + grow) * D_MODEL + k0 + gcol,
                     lds_a + chunk * 512);
        }
        #pragma unroll
        for (int c = 0; c < NCB; c++) {
            int chunk = w * NCB + c;
            gl2lds16(W + (wn0 + chunk * 8 + grow) * D_MODEL + k0 + gcol,
                     lds_b + chunk * 512);
        }
        __syncthreads();

        bf16x8 af[4][2], bf[NT][2];
        #pragma unroll
        for (int mt = 0; mt < 4; mt++)
            #pragma unroll
            for (int ks = 0; ks < 2; ks++)
                af[mt][ks] = *(const bf16x8*)(lds_a + (wm + mt * 16 + lrow) * 64 +
                                              (((ks * 4 + lq) ^ sw8) * 8));
        #pragma unroll
        for (int nt = 0; nt < NT; nt++)
            #pragma unroll
            for (int ks = 0; ks < 2; ks++)
                bf[nt][ks] = *(const bf16x8*)(lds_b + (wn + nt * 16 + lrow) * 64 +
                                              (((ks * 4 + lq) ^ sw8) * 8));
        #pragma unroll
        for (int mt = 0; mt < 4; mt++)
            #pragma unroll
            for (int nt = 0; nt < NT; nt++)
                #pragma unroll
                for (int ks = 0; ks < 2; ks++)
                    acc[mt][nt] = mfma16(af[mt][ks], bf[nt][ks], acc[mt][nt]);
        __syncthreads();
    }

    if (MODE == 0) {
        int tensor = by >> 3;                    // 0=Q 1=K 2=V
        int nbase = (by & 7) * 128;
        const float* bias = tensor == 0 ? b0 : tensor == 1 ? b1 : b2;
        float scale = tensor == 0 ? QSCALE : 1.0f;
        if (tensor < 2) {
            unsigned short* outt = out_bf + (size_t)tensor * (32u * T_SEQ * DH);
            #pragma unroll
            for (int mt = 0; mt < 4; mt++) {
                #pragma unroll
                for (int nt = 0; nt < NT; nt++) {
                    int n = nbase + wn + nt * 16 + lrow;     // n' = h*64+d
                    int h = n >> 6, d = n & 63;
                    float bb = bias[d * 16 + h];
                    #pragma unroll
                    for (int r = 0; r < 4; r++) {
                        int row = (int)am0 + wm + mt * 16 + lq * 4 + r;
                        float v = (acc[mt][nt][r] + bb) * scale;
                        int b = row >> 11, i = row & 2047;
                        long idx = ((long)(b * 16 + h) * T_SEQ + i) * DH + d;
                        outt[idx] = f32_bf16(v);
                    }
                }
            }
        } else {
            int row0 = (int)am0 + wm;                    // multiple of 64
            int b = row0 >> 11;
            int blk = (row0 & 2047) >> 6;
            #pragma unroll
            for (int nt = 0; nt < NT; nt++) {
                int n = nbase + wn + nt * 16 + lrow;
                int h = n >> 6, d = n & 63;
                float bb = bias[d * 16 + h];
                long base = (((long)(b * 16 + h) * 64 + d) * 32 + blk) * 64;
                #pragma unroll
                for (int mt = 0; mt < 4; mt++) {
                    uint2 o;
                    o.x = pack2_bf16(acc[mt][nt][0] + bb, acc[mt][nt][1] + bb);
                    o.y = pack2_bf16(acc[mt][nt][2] + bb, acc[mt][nt][3] + bb);
                    *(uint2*)(vtg + base + lq * 16 + mt * 4) = o;
                }
            }
        }
    } else {
        #pragma unroll
        for (int mt = 0; mt < 4; mt++) {
            #pragma unroll
            for (int nt = 0; nt < NT; nt++) {
                int n = (int)wn0 + wn + nt * 16 + lrow;
                float bb = b0[n];
                #pragma unroll
                for (int r = 0; r < 4; r++) {
                    int row = (int)am0 + wm + mt * 16 + lq * 4 + r;
                    long idx = (long)row * D_MODEL + n;
                    out_f32[idx] = acc[mt][nt][r] + bb + resid[idx];
                }
            }
        }
    }
}

// ---------------- attention core (round-6 structure, templated j-range) ----------
// JS = number of j-splits. JS=1: full pass, normalize + write att directly.
// JS=2: process half the j-range; write unnormalized bf16 O-partial + fp32 l-partial.
template <int JS>
__global__ __launch_bounds__(256) void k_attn(const unsigned short* __restrict__ q_ws,
                                              const unsigned short* __restrict__ k_ws,
                                              const unsigned short* __restrict__ vtg,
                                              unsigned short* __restrict__ att,
                                              unsigned short* __restrict__ opart,
                                              float* __restrict__ lpart) {
    __shared__ unsigned short kbuf[2 * 64 * 64];
    __shared__ unsigned short vbuf[2 * 64 * 64];
    const int tid = threadIdx.x;
    const int w = tid >> 6, l = tid & 63;
    const int lrow = l & 15, lq = l >> 4;
    const int sw = lrow & 7;
    const int L = blockIdx.x;
    const int bh = (L & 7) * 4 + ((L >> 3) & 3);   // 4 bh per XCD -> K/V L2-resident
    const int rest = L >> 5;
    const int i0 = (JS == 1 ? rest : (rest & 15)) * 128;
    const int s = (JS == 1 ? 0 : (rest >> 4));
    constexpr int NTILE = (T_SEQ / 64) / JS;
    const int jt0 = s * NTILE;
    const unsigned short* kh = k_ws + (long)bh * T_SEQ * DH;
    const unsigned short* vh = vtg + (long)bh * 64 * T_SEQ;  // [d][blk][j']

    const int rl = l >> 3;                     // staging: row within 8-row chunk
    const int gl = ((l & 7) ^ rl) * 8;         // staging: swizzled granule (shorts)

    bf16x8 qf[2][2];
    #pragma unroll
    for (int qt = 0; qt < 2; qt++) {
        const unsigned short* qp =
            q_ws + ((long)bh * T_SEQ + i0 + w * 32 + qt * 16 + lrow) * DH + lq * 8;
        qf[qt][0] = *(const bf16x8*)qp;
        qf[qt][1] = *(const bf16x8*)(qp + 32);
    }
    floatx4 o_acc[2][4] = {};
    floatx4 l_acc[2] = {};
    const short4v ones = {0x3F80, 0x3F80, 0x3F80, 0x3F80};

    // stage tile jt into buffer sel (4 global_load_lds per thread: 2 K + 2 V)
    auto stage = [&](int jt, int sel) {
        unsigned short* kd = kbuf + sel * 4096 + (w * 2) * 512;
        unsigned short* vd = vbuf + sel * 4096 + (w * 2) * 512;
        #pragma unroll
        for (int c = 0; c < 2; c++) {
            int row = w * 16 + c * 8 + rl;     // 0..63
            gl2lds16(kh + ((long)(jt * 64 + row)) * 64 + gl, kd + c * 512);
            gl2lds16(vh + ((long)row * 32 + jt) * 64 + gl, vd + c * 512);
        }
    };

    stage(jt0, 0);

    for (int u = 0; u < NTILE; u++) {
        const int jt = jt0 + u;
        const int cur = u & 1;
        if (u < NTILE - 1) {
            stage(jt + 1, 1 - cur);
            __builtin_amdgcn_s_waitcnt(WAITCNT_VM4);   // drain prev tile, keep prefetch
        } else {
            __builtin_amdgcn_s_waitcnt(WAITCNT_VM0);
        }
        __builtin_amdgcn_s_barrier();

        const unsigned short* kb_ = kbuf + cur * 4096;
        const unsigned short* vb_ = vbuf + cur * 4096;

        // S^T - 10 for both q-tiles; K-frags read once (single-granule b128s)
        floatx4 s0[4], s1[4];
        #pragma unroll
        for (int nt = 0; nt < 4; nt++) {
            const unsigned short* kp = kb_ + (nt * 16 + lrow) * 64;
            bf16x8 ka = *(const bf16x8*)(kp + ((lq ^ sw) * 8));
            bf16x8 kb = *(const bf16x8*)(kp + (((lq + 4) ^ sw) * 8));
            floatx4 c0 = {-EXP2_SHIFT, -EXP2_SHIFT, -EXP2_SHIFT, -EXP2_SHIFT};
            floatx4 c1 = c0;
            c0 = mfma16(ka, qf[0][0], c0);
            c0 = mfma16(kb, qf[0][1], c0);
            c1 = mfma16(ka, qf[1][0], c1);
            c1 = mfma16(kb, qf[1][1], c1);
            s0[nt] = c0;
            s1[nt] = c1;
        }
        // p = exp2(s); pack bf16 B-frags; denominators via ones-MFMA
        short4v pf0[4], pf1[4];
        #pragma unroll
        for (int nt = 0; nt < 4; nt++) {
            {
                float p0 = __builtin_amdgcn_exp2f(s0[nt][0]);
                float p1 = __builtin_amdgcn_exp2f(s0[nt][1]);
                float p2 = __builtin_amdgcn_exp2f(s0[nt][2]);
                float p3 = __builtin_amdgcn_exp2f(s0[nt][3]);
                uint2 pk;
                pk.x = __builtin_amdgcn_perm(__float_as_uint(p1), __float_as_uint(p0), 0x07060302);
                pk.y = __builtin_amdgcn_perm(__float_as_uint(p3), __float_as_uint(p2), 0x07060302);
                union { uint2 u; short4v s4; } cv; cv.u = pk;
                pf0[nt] = cv.s4;
                l_acc[0] = mfma16k16(ones, pf0[nt], l_acc[0]);
            }
            {
                float p0 = __builtin_amdgcn_exp2f(s1[nt][0]);
                float p1 = __builtin_amdgcn_exp2f(s1[nt][1]);
                float p2 = __builtin_amdgcn_exp2f(s1[nt][2]);
                float p3 = __builtin_amdgcn_exp2f(s1[nt][3]);
                uint2 pk;
                pk.x = __builtin_amdgcn_perm(__float_as_uint(p1), __float_as_uint(p0), 0x07060302);
                pk.y = __builtin_amdgcn_perm(__float_as_uint(p3), __float_as_uint(p2), 0x07060302);
                union { uint2 u; short4v s4; } cv; cv.u = pk;
                pf1[nt] = cv.s4;
                l_acc[1] = mfma16k16(ones, pf1[nt], l_acc[1]);
            }
        }
        // O^T += V^T * P — V-frags read once (single-granule reads), both q-tiles
        #pragma unroll
        for (int dt = 0; dt < 4; dt++) {
            const unsigned short* vp = vb_ + (dt * 16 + lrow) * 64;
            short8v v01 = *(const short8v*)(vp + (((2 * lq) ^ sw) * 8));
            short8v v23 = *(const short8v*)(vp + (((2 * lq + 1) ^ sw) * 8));
            short4v va = __builtin_shufflevector(v01, v01, 0, 1, 2, 3);
            short4v vb = __builtin_shufflevector(v01, v01, 4, 5, 6, 7);
            short4v vc = __builtin_shufflevector(v23, v23, 0, 1, 2, 3);
            short4v vd = __builtin_shufflevector(v23, v23, 4, 5, 6, 7);
            o_acc[0][dt] = mfma16k16(va, pf0[0], o_acc[0][dt]);
            o_acc[0][dt] = mfma16k16(vb, pf0[1], o_acc[0][dt]);
            o_acc[0][dt] = mfma16k16(vc, pf0[2], o_acc[0][dt]);
            o_acc[0][dt] = mfma16k16(vd, pf0[3], o_acc[0][dt]);
            o_acc[1][dt] = mfma16k16(va, pf1[0], o_acc[1][dt]);
            o_acc[1][dt] = mfma16k16(vb, pf1[1], o_acc[1][dt]);
            o_acc[1][dt] = mfma16k16(vc, pf1[2], o_acc[1][dt]);
            o_acc[1][dt] = mfma16k16(vd, pf1[3], o_acc[1][dt]);
        }
        __syncthreads();   // all reads of buf[cur] done before it is re-staged
    }

    if (JS == 1) {
        int h = bh & 15, b = bh >> 4;
        #pragma unroll
        for (int qt = 0; qt < 2; qt++) {
            float rl2 = 1.0f / l_acc[qt][0];
            int i = i0 + w * 32 + qt * 16 + lrow;
            unsigned short* orow = att + ((long)(b * T_SEQ + i)) * D_MODEL + h * 64;
            #pragma unroll
            for (int dt = 0; dt < 4; dt++) {
                uint2 o;
                o.x = pack2_bf16(o_acc[qt][dt][0] * rl2, o_acc[qt][dt][1] * rl2);
                o.y = pack2_bf16(o_acc[qt][dt][2] * rl2, o_acc[qt][dt][3] * rl2);
                *(uint2*)(orow + dt * 16 + lq * 4) = o;
            }
        }
    } else {
        // partial write: opart[((s*32+bh)*T + i)*64 + d] (bf16, unnormalized), lpart fp32
        #pragma unroll
        for (int qt = 0; qt < 2; qt++) {
            int i = i0 + w * 32 + qt * 16 + lrow;
            long base = (((long)(s * 32 + bh)) * T_SEQ + i) * 64;
            #pragma unroll
            for (int dt = 0; dt < 4; dt++) {
                uint2 o;
                o.x = pack2_bf16(o_acc[qt][dt][0], o_acc[qt][dt][1]);
                o.y = pack2_bf16(o_acc[qt][dt][2], o_acc[qt][dt][3]);
                *(uint2*)(opart + base + dt * 16 + lq * 4) = o;
            }
            if (lq == 0)
                lpart[((long)(s * 32 + bh)) * T_SEQ + i] = l_acc[qt][0];
        }
    }
}

// ---------------- combine partials -> att (bf16, head-contiguous) ----------------
__global__ __launch_bounds__(256) void k_combine(const unsigned short* __restrict__ opart,
                                                 const float* __restrict__ lpart,
                                                 unsigned short* __restrict__ att) {
    int blk = blockIdx.x;                 // bh*64 + ichunk
    int bh = blk >> 6, ic = blk & 63;
    int t = threadIdx.x;
    int il = t >> 3, dg = (t & 7) * 8;
    long i = (long)ic * 32 + il;
    long base0 = (((long)bh) * T_SEQ + i) * 64 + dg;
    long base1 = (((long)(32 + bh)) * T_SEQ + i) * 64 + dg;
    uint4 a = *(const uint4*)(opart + base0);
    uint4 b4 = *(const uint4*)(opart + base1);
    float rl = 1.0f / (lpart[(long)bh * T_SEQ + i] + lpart[(long)(32 + bh) * T_SEQ + i]);
    unsigned int ua[4] = {a.x, a.y, a.z, a.w};
    unsigned int ub[4] = {b4.x, b4.y, b4.z, b4.w};
    unsigned int uo[4];
    #pragma unroll
    for (int k = 0; k < 4; k++) {
        float a0 = __uint_as_float((ua[k] & 0xFFFFu) << 16);
        float a1 = __uint_as_float(ua[k] & 0xFFFF0000u);
        float b0 = __uint_as_float((ub[k] & 0xFFFFu) << 16);
        float b1 = __uint_as_float(ub[k] & 0xFFFF0000u);
        uo[k] = pack2_bf16((a0 + b0) * rl, (a1 + b1) * rl);
    }
    int h = bh & 15, b = bh >> 4;
    unsigned short* dst = att + ((long)(b * T_SEQ + i)) * D_MODEL + h * 64 + dg;
    uint4 o; o.x = uo[0]; o.y = uo[1]; o.z = uo[2]; o.w = uo[3];
    *(uint4*)dst = o;
}

// ---------------- LayerNorm in-place on d_out ----------------
__global__ __launch_bounds__(256) void k_ln(float* __restrict__ io,
                                            const float* __restrict__ gamma,
                                            const float* __restrict__ beta) {
    int row = blockIdx.x, t = threadIdx.x;
    float* p = io + (long)row * D_MODEL + t * 4;
    float4 v = *(float4*)p;
    float s = v.x + v.y + v.z + v.w;
    float ss = v.x * v.x + v.y * v.y + v.z * v.z + v.w * v.w;
    #pragma unroll
    for (int m = 1; m < 64; m <<= 1) {
        s += __shfl_xor(s, m);
        ss += __shfl_xor(ss, m);
    }
    __shared__ float red[8];
    if ((t & 63) == 0) { red[t >> 6] = s; red[4 + (t >> 6)] = ss; }
    __syncthreads();
    s = red[0] + red[1] + red[2] + red[3];
    ss = red[4] + red[5] + red[6] + red[7];
    float mu = s * (1.0f / 1024.0f);
    float var = ss * (1.0f / 1024.0f) - mu * mu;
    float rstd = rsqrtf(var + 1e-5f);
    float4 g = *(const float4*)(gamma + t * 4);
    float4 be = *(const float4*)(beta + t * 4);
    float4 o;
    o.x = (v.x - mu) * rstd * g.x + be.x;
    o.y = (v.y - mu) * rstd * g.y + be.y;
    o.z = (v.z - mu) * rstd * g.z + be.z;
    o.w = (v.w - mu) * rstd * g.w + be.w;
    *(float4*)p = o;
}

extern "C" void kernel_launch(void* const* d_in, const int* in_sizes, int n_in,
                              void* d_out, int out_size, void* d_ws, size_t ws_size,
                              hipStream_t stream) {
    const float* x = (const float*)d_in[0];
    const float* Wq = (const float*)d_in[1];
    const float* bq = (const float*)d_in[2];
    const float* Wk = (const float*)d_in[3];
    const float* bk = (const float*)d_in[4];
    const float* Wv = (const float*)d_in[5];
    const float* bv = (const float*)d_in[6];
    const float* Wo = (const float*)d_in[7];
    const float* bo = (const float*)d_in[8];
    const float* gamma = (const float*)d_in[9];
    const float* beta = (const float*)d_in[10];
    float* out = (float*)d_out;

    char* ws = (char*)d_ws;
    unsigned short* x_bf = (unsigned short*)(ws);                       // 0-8 MB (reused as att)
    unsigned short* wqkv_bf = (unsigned short*)(ws + ((size_t)8 << 20));// 8-14 MB
    unsigned short* wo_bf = (unsigned short*)(ws + ((size_t)14 << 20)); // 14-16 MB
    unsigned short* qkv_ws = (unsigned short*)(ws + ((size_t)16 << 20));// 16-40 MB (q|k|vt)
    unsigned short* opart = (unsigned short*)(ws + ((size_t)40 << 20)); // 40-56 MB
    float* lpart = (float*)(ws + ((size_t)56 << 20));                   // 56-56.5 MB
    unsigned short* att = x_bf;  // alias: x_bf dead after QKV GEMM

    unsigned short* q_ws = qkv_ws;
    unsigned short* k_ws = qkv_ws + (size_t)32 * T_SEQ * DH;
    unsigned short* vtg = qkv_ws + (size_t)64 * T_SEQ * DH;

    const bool use_split = ws_size >= ((size_t)60 << 20);

    k_conv_all<<<8192, 256, 0, stream>>>(x, Wq, Wk, Wv, Wo, x_bf, wqkv_bf, wo_bf);

    // fused QKV GEMM: N = 3072, 1D grid with XCD swizzle
    k_gemm<128, 0><<<768, 256, 0, stream>>>(
        x_bf, wqkv_bf, bq, bk, bv, nullptr, qkv_ws, vtg, nullptr);

    if (use_split) {
        k_attn<2><<<1024, 256, 0, stream>>>(q_ws, k_ws, vtg, nullptr, opart, lpart);
        k_combine<<<2048, 256, 0, stream>>>(opart, lpart, att);
    } else {
        k_attn<1><<<512, 256, 0, stream>>>(q_ws, k_ws, vtg, att, nullptr, nullptr);
    }

    // O-projection + bias + residual: N = 1024, 1D grid with XCD swizzle
    k_gemm<64, 1><<<512, 256, 0, stream>>>(
        att, wo_bf, bo, nullptr, nullptr, x, nullptr, nullptr, out);

    k_ln<<<NROWS, 256, 0, stream>>>(out, gamma, beta);
}

// Round 9
// 212.727 us; speedup vs baseline: 1.1188x; 1.0455x over previous
//
#include <hip/hip_runtime.h>
#include <stdint.h>

#define T_SEQ 2048
#define D_MODEL 1024
#define NH 16
#define DH 64
#define NROWS 4096  // B*T

typedef __bf16 bf16x8 __attribute__((ext_vector_type(8)));
typedef float floatx4 __attribute__((ext_vector_type(4)));
typedef short short4v __attribute__((ext_vector_type(4)));
typedef short short8v __attribute__((ext_vector_type(8)));

#define AS1 __attribute__((address_space(1)))
#define AS3 __attribute__((address_space(3)))

static __device__ __forceinline__ void gl2lds16(const unsigned short* g, unsigned short* s) {
    __builtin_amdgcn_global_load_lds((const AS1 unsigned int*)g, (AS3 unsigned int*)s, 16, 0, 0);
}

static __device__ __forceinline__ unsigned short f32_bf16(float f) {
    union { float f; unsigned int u; } c; c.f = f;
    unsigned int u = c.u;
    u = u + 0x7FFFu + ((u >> 16) & 1u);   // RNE
    return (unsigned short)(u >> 16);
}

static __device__ __forceinline__ unsigned int pack2_bf16(float a, float b) {
    return (unsigned int)f32_bf16(a) | ((unsigned int)f32_bf16(b) << 16);
}

static __device__ __forceinline__ floatx4 mfma16(bf16x8 a, bf16x8 b, floatx4 c) {
    return __builtin_amdgcn_mfma_f32_16x16x32_bf16(a, b, c, 0, 0, 0);
}

static __device__ __forceinline__ floatx4 mfma16k16(short4v a, short4v b, floatx4 c) {
#if defined(__HIP_DEVICE_COMPILE__)
    return __builtin_amdgcn_mfma_f32_16x16x16bf16_1k(a, b, c, 0, 0, 0);
#else
    (void)a; (void)b;
    return c;  // host stub — never executed
#endif
}

#define QSCALE 0.1803368801111204f   // (1/8) * log2(e); softmax in exp2 domain
#define EXP2_SHIFT 10.0f
// s_waitcnt imm: vmcnt[3:0], expcnt[6:4]=7 (nowait), lgkmcnt[11:8]=0xF (nowait)
#define WAITCNT_VM(n) (0x0F70 | (n))

// ---------------- fused conversion kernel ----------------
__global__ __launch_bounds__(256) void k_conv_all(const float* __restrict__ x,
                                                  const float* __restrict__ Wq,
                                                  const float* __restrict__ Wk,
                                                  const float* __restrict__ Wv,
                                                  const float* __restrict__ Wo,
                                                  unsigned short* __restrict__ x_bf,
                                                  unsigned short* __restrict__ wqkv_bf,
                                                  unsigned short* __restrict__ wo_bf) {
    int b = blockIdx.x, t = threadIdx.x;
    if (b < 4096) {
        int i = b * 1024 + t * 4;
        float4 v = *(const float4*)(x + i);
        uint2 o;
        o.x = pack2_bf16(v.x, v.y);
        o.y = pack2_bf16(v.z, v.w);
        *(uint2*)(x_bf + i) = o;
    } else if (b < 7168) {
        int idx = b - 4096;
        int tensor = idx >> 10, np = idx & 1023;
        const float* src = tensor == 0 ? Wq : tensor == 1 ? Wk : Wv;
        int f = (np & 63) * 16 + (np >> 6);
        int c = t * 4;
        float4 v = *(const float4*)(src + (long)f * D_MODEL + c);
        uint2 o;
        o.x = pack2_bf16(v.x, v.y);
        o.y = pack2_bf16(v.z, v.w);
        *(uint2*)(wqkv_bf + ((long)tensor * D_MODEL + np) * D_MODEL + c) = o;
    } else {
        int n = b - 7168;
        int fp = t * 4;
        const float* row = Wo + (long)n * D_MODEL;
        unsigned short o[4];
        #pragma unroll
        for (int k = 0; k < 4; k++) {
            int f = fp + k;
            o[k] = f32_bf16(row[(f & 63) * 16 + (f >> 6)]);
        }
        *(uint2*)(wo_bf + (long)n * D_MODEL + fp) = *(const uint2*)o;
    }
}

// ---------------- GEMM: C = A(bf16) @ W(bf16)^T, K = 1024 ----------------
// Double-buffered LDS K-loop; raw s_barrier + manual partial vmcnt — no compiler
// vmcnt(0) drains anywhere in the loop. XOR-swizzled LDS, XCD-aware block swizzle.
// MODE 0: fused QKV (W stacked 3072x1024); grid 768. MODE 1: O-proj; grid 512.
template <int BN, int MODE>
__global__ __launch_bounds__(256) void k_gemm(const unsigned short* __restrict__ A,
                                              const unsigned short* __restrict__ W,
                                              const float* __restrict__ b0,
                                              const float* __restrict__ b1,
                                              const float* __restrict__ b2,
                                              const float* __restrict__ resid,
                                              unsigned short* __restrict__ out_bf,
                                              unsigned short* __restrict__ vtg,
                                              float* __restrict__ out_f32) {
    constexpr int NT = BN / 32;
    constexpr int NCB = BN / 32;
    constexpr int NDMA = 4 + NCB;            // DMA instrs per thread per stage
    __shared__ unsigned short lds_a[2 * 128 * 64];
    __shared__ unsigned short lds_b[2 * BN * 64];
    const int tid = threadIdx.x;
    const int w = tid >> 6, l = tid & 63;
    const int lrow = l & 15, lq = l >> 4;
    const int wm = (w >> 1) * 64, wn = (w & 1) * (BN / 2);
    const int L = blockIdx.x;
    const int bx = (L & 7) * 4 + ((L >> 3) & 3);
    const int by = L >> 5;
    const long am0 = (long)bx * 128;
    const long wn0 = (long)by * BN;

    floatx4 acc[4][NT] = {};
    const int grow = l >> 3;
    const int gcol = ((l & 7) ^ grow) * 8;   // column-group XOR swizzle (global side)
    const int sw8 = (lrow & 7);

    auto stage = [&](int ki, int sel) {
        unsigned short* la = lds_a + sel * 8192;
        unsigned short* lb = lds_b + sel * (BN * 64);
        int k0 = ki * 64;
        #pragma unroll
        for (int c = 0; c < 4; c++) {
            int chunk = w * 4 + c;
            gl2lds16(A + (am0 + chunk * 8 + grow) * D_MODEL + k0 + gcol, la + chunk * 512);
        }
        #pragma unroll
        for (int c = 0; c < NCB; c++) {
            int chunk = w * NCB + c;
            gl2lds16(W + (wn0 + chunk * 8 + grow) * D_MODEL + k0 + gcol, lb + chunk * 512);
        }
    };

    stage(0, 0);

    for (int i = 0; i < 16; i++) {
        const int cur = i & 1;
        if (i < 15) {
            stage(i + 1, 1 - cur);
            __builtin_amdgcn_s_waitcnt(WAITCNT_VM(NDMA));  // drain stage(i), keep stage(i+1)
        } else {
            __builtin_amdgcn_s_waitcnt(WAITCNT_VM(0));
        }
        __builtin_amdgcn_s_barrier();

        const unsigned short* la = lds_a + cur * 8192;
        const unsigned short* lb = lds_b + cur * (BN * 64);
        bf16x8 af[4][2], bf[NT][2];
        #pragma unroll
        for (int mt = 0; mt < 4; mt++)
            #pragma unroll
            for (int ks = 0; ks < 2; ks++)
                af[mt][ks] = *(const bf16x8*)(la + (wm + mt * 16 + lrow) * 64 +
                                              (((ks * 4 + lq) ^ sw8) * 8));
        #pragma unroll
        for (int nt = 0; nt < NT; nt++)
            #pragma unroll
            for (int ks = 0; ks < 2; ks++)
                bf[nt][ks] = *(const bf16x8*)(lb + (wn + nt * 16 + lrow) * 64 +
                                              (((ks * 4 + lq) ^ sw8) * 8));
        #pragma unroll
        for (int mt = 0; mt < 4; mt++)
            #pragma unroll
            for (int nt = 0; nt < NT; nt++)
                #pragma unroll
                for (int ks = 0; ks < 2; ks++)
                    acc[mt][nt] = mfma16(af[mt][ks], bf[nt][ks], acc[mt][nt]);
        __builtin_amdgcn_s_barrier();   // raw: reads of buf[cur] done before restage (i+2)
    }

    if (MODE == 0) {
        int tensor = by >> 3;                    // 0=Q 1=K 2=V
        int nbase = (by & 7) * 128;
        const float* bias = tensor == 0 ? b0 : tensor == 1 ? b1 : b2;
        float scale = tensor == 0 ? QSCALE : 1.0f;
        if (tensor < 2) {
            unsigned short* outt = out_bf + (size_t)tensor * (32u * T_SEQ * DH);
            #pragma unroll
            for (int mt = 0; mt < 4; mt++) {
                #pragma unroll
                for (int nt = 0; nt < NT; nt++) {
                    int n = nbase + wn + nt * 16 + lrow;     // n' = h*64+d
                    int h = n >> 6, d = n & 63;
                    float bb = bias[d * 16 + h];
                    #pragma unroll
                    for (int r = 0; r < 4; r++) {
                        int row = (int)am0 + wm + mt * 16 + lq * 4 + r;
                        float v = (acc[mt][nt][r] + bb) * scale;
                        int b = row >> 11, i = row & 2047;
                        long idx = ((long)(b * 16 + h) * T_SEQ + i) * DH + d;
                        outt[idx] = f32_bf16(v);
                    }
                }
            }
        } else {
            int row0 = (int)am0 + wm;                    // multiple of 64
            int b = row0 >> 11;
            int blk = (row0 & 2047) >> 6;
            #pragma unroll
            for (int nt = 0; nt < NT; nt++) {
                int n = nbase + wn + nt * 16 + lrow;
                int h = n >> 6, d = n & 63;
                float bb = bias[d * 16 + h];
                long base = (((long)(b * 16 + h) * 64 + d) * 32 + blk) * 64;
                #pragma unroll
                for (int mt = 0; mt < 4; mt++) {
                    uint2 o;
                    o.x = pack2_bf16(acc[mt][nt][0] + bb, acc[mt][nt][1] + bb);
                    o.y = pack2_bf16(acc[mt][nt][2] + bb, acc[mt][nt][3] + bb);
                    *(uint2*)(vtg + base + lq * 16 + mt * 4) = o;
                }
            }
        }
    } else {
        #pragma unroll
        for (int mt = 0; mt < 4; mt++) {
            #pragma unroll
            for (int nt = 0; nt < NT; nt++) {
                int n = (int)wn0 + wn + nt * 16 + lrow;
                float bb = b0[n];
                #pragma unroll
                for (int r = 0; r < 4; r++) {
                    int row = (int)am0 + wm + mt * 16 + lq * 4 + r;
                    long idx = (long)row * D_MODEL + n;
                    out_f32[idx] = acc[mt][nt][r] + bb + resid[idx];
                }
            }
        }
    }
}

// ---------------- attention: S^T trick + async double-buffered K/V pipeline --------
// r6 structure; both barriers are RAW s_barrier (no compiler vmcnt/lgkm drains).
// Top: manual vmcnt(4) drains prev tile's DMA while next tile's stays in flight.
__global__ __launch_bounds__(256) void k_attn(const unsigned short* __restrict__ q_ws,
                                              const unsigned short* __restrict__ k_ws,
                                              const unsigned short* __restrict__ vtg,
                                              unsigned short* __restrict__ att) {
    __shared__ unsigned short kbuf[2 * 64 * 64];
    __shared__ unsigned short vbuf[2 * 64 * 64];
    const int tid = threadIdx.x;
    const int w = tid >> 6, l = tid & 63;
    const int lrow = l & 15, lq = l >> 4;
    const int sw = lrow & 7;
    const int L = blockIdx.x;
    const int bh = (L & 7) * 4 + ((L >> 3) & 3);   // 4 bh per XCD -> K/V L2-resident
    const int i0 = (L >> 5) * 128;
    const unsigned short* kh = k_ws + (long)bh * T_SEQ * DH;
    const unsigned short* vh = vtg + (long)bh * 64 * T_SEQ;  // [d][blk][j']

    const int rl = l >> 3;                     // staging: row within 8-row chunk
    const int gl = ((l & 7) ^ rl) * 8;         // staging: swizzled granule (shorts)

    bf16x8 qf[2][2];
    #pragma unroll
    for (int qt = 0; qt < 2; qt++) {
        const unsigned short* qp =
            q_ws + ((long)bh * T_SEQ + i0 + w * 32 + qt * 16 + lrow) * DH + lq * 8;
        qf[qt][0] = *(const bf16x8*)qp;
        qf[qt][1] = *(const bf16x8*)(qp + 32);
    }
    floatx4 o_acc[2][4] = {};
    floatx4 l_acc[2] = {};
    const short4v ones = {0x3F80, 0x3F80, 0x3F80, 0x3F80};

    auto stage = [&](int jt, int sel) {
        unsigned short* kd = kbuf + sel * 4096 + (w * 2) * 512;
        unsigned short* vd = vbuf + sel * 4096 + (w * 2) * 512;
        #pragma unroll
        for (int c = 0; c < 2; c++) {
            int row = w * 16 + c * 8 + rl;     // 0..63
            gl2lds16(kh + ((long)(jt * 64 + row)) * 64 + gl, kd + c * 512);
            gl2lds16(vh + ((long)row * 32 + jt) * 64 + gl, vd + c * 512);
        }
    };

    stage(0, 0);

    constexpr int NTILE = T_SEQ / 64;
    for (int jt = 0; jt < NTILE; jt++) {
        const int cur = jt & 1;
        if (jt < NTILE - 1) {
            stage(jt + 1, 1 - cur);
            __builtin_amdgcn_s_waitcnt(WAITCNT_VM(4));   // drain tile jt, keep jt+1
        } else {
            __builtin_amdgcn_s_waitcnt(WAITCNT_VM(0));
        }
        __builtin_amdgcn_s_barrier();

        const unsigned short* kb_ = kbuf + cur * 4096;
        const unsigned short* vb_ = vbuf + cur * 4096;

        // S^T - 10 for both q-tiles; K-frags read once (single-granule b128s)
        floatx4 s0[4], s1[4];
        #pragma unroll
        for (int nt = 0; nt < 4; nt++) {
            const unsigned short* kp = kb_ + (nt * 16 + lrow) * 64;
            bf16x8 ka = *(const bf16x8*)(kp + ((lq ^ sw) * 8));
            bf16x8 kb = *(const bf16x8*)(kp + (((lq + 4) ^ sw) * 8));
            floatx4 c0 = {-EXP2_SHIFT, -EXP2_SHIFT, -EXP2_SHIFT, -EXP2_SHIFT};
            floatx4 c1 = c0;
            c0 = mfma16(ka, qf[0][0], c0);
            c0 = mfma16(kb, qf[0][1], c0);
            c1 = mfma16(ka, qf[1][0], c1);
            c1 = mfma16(kb, qf[1][1], c1);
            s0[nt] = c0;
            s1[nt] = c1;
        }
        // p = exp2(s); pack bf16 B-frags; denominators via ones-MFMA
        short4v pf0[4], pf1[4];
        #pragma unroll
        for (int nt = 0; nt < 4; nt++) {
            {
                float p0 = __builtin_amdgcn_exp2f(s0[nt][0]);
                float p1 = __builtin_amdgcn_exp2f(s0[nt][1]);
                float p2 = __builtin_amdgcn_exp2f(s0[nt][2]);
                float p3 = __builtin_amdgcn_exp2f(s0[nt][3]);
                uint2 pk;
                pk.x = __builtin_amdgcn_perm(__float_as_uint(p1), __float_as_uint(p0), 0x07060302);
                pk.y = __builtin_amdgcn_perm(__float_as_uint(p3), __float_as_uint(p2), 0x07060302);
                union { uint2 u; short4v s4; } cv; cv.u = pk;
                pf0[nt] = cv.s4;
                l_acc[0] = mfma16k16(ones, pf0[nt], l_acc[0]);
            }
            {
                float p0 = __builtin_amdgcn_exp2f(s1[nt][0]);
                float p1 = __builtin_amdgcn_exp2f(s1[nt][1]);
                float p2 = __builtin_amdgcn_exp2f(s1[nt][2]);
                float p3 = __builtin_amdgcn_exp2f(s1[nt][3]);
                uint2 pk;
                pk.x = __builtin_amdgcn_perm(__float_as_uint(p1), __float_as_uint(p0), 0x07060302);
                pk.y = __builtin_amdgcn_perm(__float_as_uint(p3), __float_as_uint(p2), 0x07060302);
                union { uint2 u; short4v s4; } cv; cv.u = pk;
                pf1[nt] = cv.s4;
                l_acc[1] = mfma16k16(ones, pf1[nt], l_acc[1]);
            }
        }
        // O^T += V^T * P — V-frags read once (single-granule reads), both q-tiles
        #pragma unroll
        for (int dt = 0; dt < 4; dt++) {
            const unsigned short* vp = vb_ + (dt * 16 + lrow) * 64;
            short8v v01 = *(const short8v*)(vp + (((2 * lq) ^ sw) * 8));
            short8v v23 = *(const short8v*)(vp + (((2 * lq + 1) ^ sw) * 8));
            short4v va = __builtin_shufflevector(v01, v01, 0, 1, 2, 3);
            short4v vb = __builtin_shufflevector(v01, v01, 4, 5, 6, 7);
            short4v vc = __builtin_shufflevector(v23, v23, 0, 1, 2, 3);
            short4v vd = __builtin_shufflevector(v23, v23, 4, 5, 6, 7);
            o_acc[0][dt] = mfma16k16(va, pf0[0], o_acc[0][dt]);
            o_acc[0][dt] = mfma16k16(vb, pf0[1], o_acc[0][dt]);
            o_acc[0][dt] = mfma16k16(vc, pf0[2], o_acc[0][dt]);
            o_acc[0][dt] = mfma16k16(vd, pf0[3], o_acc[0][dt]);
            o_acc[1][dt] = mfma16k16(va, pf1[0], o_acc[1][dt]);
            o_acc[1][dt] = mfma16k16(vb, pf1[1], o_acc[1][dt]);
            o_acc[1][dt] = mfma16k16(vc, pf1[2], o_acc[1][dt]);
            o_acc[1][dt] = mfma16k16(vd, pf1[3], o_acc[1][dt]);
        }
        __builtin_amdgcn_s_barrier();   // raw: all reads of buf[cur] done before restage
    }
    int h = bh & 15, b = bh >> 4;
    #pragma unroll
    for (int qt = 0; qt < 2; qt++) {
        float rl2 = 1.0f / l_acc[qt][0];
        int i = i0 + w * 32 + qt * 16 + lrow;
        unsigned short* orow = att + ((long)(b * T_SEQ + i)) * D_MODEL + h * 64;
        #pragma unroll
        for (int dt = 0; dt < 4; dt++) {
            uint2 o;
            o.x = pack2_bf16(o_acc[qt][dt][0] * rl2, o_acc[qt][dt][1] * rl2);
            o.y = pack2_bf16(o_acc[qt][dt][2] * rl2, o_acc[qt][dt][3] * rl2);
            *(uint2*)(orow + dt * 16 + lq * 4) = o;
        }
    }
}

// ---------------- LayerNorm in-place on d_out ----------------
__global__ __launch_bounds__(256) void k_ln(float* __restrict__ io,
                                            const float* __restrict__ gamma,
                                            const float* __restrict__ beta) {
    int row = blockIdx.x, t = threadIdx.x;
    float* p = io + (long)row * D_MODEL + t * 4;
    float4 v = *(float4*)p;
    float s = v.x + v.y + v.z + v.w;
    float ss = v.x * v.x + v.y * v.y + v.z * v.z + v.w * v.w;
    #pragma unroll
    for (int m = 1; m < 64; m <<= 1) {
        s += __shfl_xor(s, m);
        ss += __shfl_xor(ss, m);
    }
    __shared__ float red[8];
    if ((t & 63) == 0) { red[t >> 6] = s; red[4 + (t >> 6)] = ss; }
    __syncthreads();
    s = red[0] + red[1] + red[2] + red[3];
    ss = red[4] + red[5] + red[6] + red[7];
    float mu = s * (1.0f / 1024.0f);
    float var = ss * (1.0f / 1024.0f) - mu * mu;
    float rstd = rsqrtf(var + 1e-5f);
    float4 g = *(const float4*)(gamma + t * 4);
    float4 be = *(const float4*)(beta + t * 4);
    float4 o;
    o.x = (v.x - mu) * rstd * g.x + be.x;
    o.y = (v.y - mu) * rstd * g.y + be.y;
    o.z = (v.z - mu) * rstd * g.z + be.z;
    o.w = (v.w - mu) * rstd * g.w + be.w;
    *(float4*)p = o;
}

extern "C" void kernel_launch(void* const* d_in, const int* in_sizes, int n_in,
                              void* d_out, int out_size, void* d_ws, size_t ws_size,
                              hipStream_t stream) {
    const float* x = (const float*)d_in[0];
    const float* Wq = (const float*)d_in[1];
    const float* bq = (const float*)d_in[2];
    const float* Wk = (const float*)d_in[3];
    const float* bk = (const float*)d_in[4];
    const float* Wv = (const float*)d_in[5];
    const float* bv = (const float*)d_in[6];
    const float* Wo = (const float*)d_in[7];
    const float* bo = (const float*)d_in[8];
    const float* gamma = (const float*)d_in[9];
    const float* beta = (const float*)d_in[10];
    float* out = (float*)d_out;

    char* ws = (char*)d_ws;
    unsigned short* x_bf = (unsigned short*)(ws);                       // 0-8 MB (reused as att)
    unsigned short* wqkv_bf = (unsigned short*)(ws + ((size_t)8 << 20));// 8-14 MB
    unsigned short* wo_bf = (unsigned short*)(ws + ((size_t)14 << 20)); // 14-16 MB
    unsigned short* qkv_ws = (unsigned short*)(ws + ((size_t)16 << 20));// 16-40 MB (q|k|vt)
    unsigned short* att = x_bf;  // alias: x_bf dead after QKV GEMM

    unsigned short* q_ws = qkv_ws;
    unsigned short* k_ws = qkv_ws + (size_t)32 * T_SEQ * DH;
    unsigned short* vtg = qkv_ws + (size_t)64 * T_SEQ * DH;

    k_conv_all<<<8192, 256, 0, stream>>>(x, Wq, Wk, Wv, Wo, x_bf, wqkv_bf, wo_bf);

    // fused QKV GEMM: N = 3072, 1D grid with XCD swizzle
    k_gemm<128, 0><<<768, 256, 0, stream>>>(
        x_bf, wqkv_bf, bq, bk, bv, nullptr, qkv_ws, vtg, nullptr);

    k_attn<<<512, 256, 0, stream>>>(q_ws, k_ws, vtg, att);

    // O-projection + bias + residual: N = 1024, 1D grid with XCD swizzle
    k_gemm<64, 1><<<512, 256, 0, stream>>>(
        att, wo_bf, bo, nullptr, nullptr, x, nullptr, nullptr, out);

    k_ln<<<NROWS, 256, 0, stream>>>(out, gamma, beta);
}